// Round 8
// baseline (1180.759 us; speedup 1.0000x reference)
//
#include <hip/hip_runtime.h>
#include <cmath>

#define D 1024
#define DFF 4096
#define NHEADS 16
#define DH 64
#define S_CACHE 512
#define SP1 513
#define NB_L 24
#define NR_L 8
#define NCH 16

typedef float v4f __attribute__((ext_vector_type(4)));

// workspace layout (float offsets)
#define WS_H      0         // [2][1024]
#define WS_H2     2048      // [2][1024]
#define WS_QKV    4096      // [16][3][2][1024] = 98304
#define WS_ATTN   102400    // [32][16][68]     = 34816
#define WS_OPROJ  137216    // [16][2][1024]    = 32768
#define WS_GU     169984    // [8][2][2][4096]  = 131072
#define WS_DOWN   301056    // [16][2][1024]    = 32768
#define WS_SPROJ  333824    // [8][2][1024]     = 16384

__device__ __forceinline__ float silu_f(float x){ return x/(1.f+expf(-x)); }

// ---------------------------------------------------------------------------
// prologue: h = hbase (+ scale * sum_ks part) -> rmsnorm(lnw) -> hn (LDS).
// Wave-shuffle reduction: 2 barriers. block 0 optionally writes raw h.
// ---------------------------------------------------------------------------
__device__ __forceinline__ void prologue_norm(
    const float* __restrict__ hbase,
    const float* __restrict__ part, int nks, float scale,
    const float* __restrict__ lnw,
    float (*hn)[D], float* __restrict__ hout)
{
  __shared__ float redw[4];
  const int t = threadIdx.x;
  const int b = t >> 7;
  const int i0 = (t & 127) * 8;
  const float4* hb4 = (const float4*)(hbase + b * D + i0);
  const float4 h0 = hb4[0], h1 = hb4[1];
  float acc[8] = {h0.x, h0.y, h0.z, h0.w, h1.x, h1.y, h1.z, h1.w};
  if (part != nullptr) {
    float s[8] = {0,0,0,0,0,0,0,0};
    for (int ks = 0; ks < nks; ++ks) {
      const float4* p4 = (const float4*)(part + (size_t)(ks * 2 + b) * D + i0);
      const float4 a = p4[0], c = p4[1];
      s[0]+=a.x; s[1]+=a.y; s[2]+=a.z; s[3]+=a.w;
      s[4]+=c.x; s[5]+=c.y; s[6]+=c.z; s[7]+=c.w;
    }
#pragma unroll
    for (int u = 0; u < 8; ++u) acc[u] += scale * s[u];
  }
  float ssq = 0.f;
#pragma unroll
  for (int u = 0; u < 8; ++u) ssq += acc[u] * acc[u];
#pragma unroll
  for (int off = 32; off; off >>= 1) ssq += __shfl_xor(ssq, off);
  if ((t & 63) == 0) redw[t >> 6] = ssq;
  __syncthreads();
  const float r = rsqrtf((redw[b * 2] + redw[b * 2 + 1]) * (1.f / D) + 1e-5f);
#pragma unroll
  for (int u = 0; u < 8; ++u) hn[b][i0 + u] = acc[u] * r * lnw[i0 + u];
  if (hout != nullptr && blockIdx.x == 0 && blockIdx.y == 0) {
    float4* o4 = (float4*)(hout + b * D + i0);
    o4[0] = make_float4(acc[0], acc[1], acc[2], acc[3]);
    o4[1] = make_float4(acc[4], acc[5], acc[6], acc[7]);
  }
  __syncthreads();
}

// ---------------------------------------------------------------------------
// QKV GEMV. grid(512): blocks 0..255 Q (16 ks x 16 j-tiles of 64 cols);
// blocks 256..511 K/V (16 ks x 8 j-tiles of 128 cols each).
// Weight tile preloaded into regs before prologue (overlap HBM with combine).
// ---------------------------------------------------------------------------
__global__ __launch_bounds__(256) void k_qkv(
    const float* __restrict__ hbase, const float* __restrict__ down_part,
    float* __restrict__ hout, const float* __restrict__ ln1,
    const float* __restrict__ wq, const float* __restrict__ wk,
    const float* __restrict__ wv,
    float* __restrict__ qkv_part, float scale, int has_prev)
{
  __shared__ float hn[2][D];
  __shared__ float redq[16][2][64];
  __shared__ float redkv[8][2][128];
  const int t = threadIdx.x;
  const int bid = blockIdx.x;
  if (bid < 256) {
    const int ks = bid >> 4, jt = bid & 15;
    const int jo4 = (t & 15) * 4;
    const int kp = t >> 4;              // 0..15
    const int ib = ks * 64 + kp * 4;
    float4 wbuf[4];
#pragma unroll
    for (int r = 0; r < 4; ++r)
      wbuf[r] = *(const float4*)(wq + (size_t)(ib + r) * D + jt * 64 + jo4);
    prologue_norm(hbase, has_prev ? down_part : nullptr, 16, scale, ln1, hn, hout);
    float a00=0,a01=0,a02=0,a03=0, a10=0,a11=0,a12=0,a13=0;
#pragma unroll
    for (int r = 0; r < 4; ++r) {
      const float x0 = hn[0][ib + r], x1 = hn[1][ib + r];
      a00 += wbuf[r].x*x0; a01 += wbuf[r].y*x0; a02 += wbuf[r].z*x0; a03 += wbuf[r].w*x0;
      a10 += wbuf[r].x*x1; a11 += wbuf[r].y*x1; a12 += wbuf[r].z*x1; a13 += wbuf[r].w*x1;
    }
    redq[kp][0][jo4+0]=a00; redq[kp][0][jo4+1]=a01; redq[kp][0][jo4+2]=a02; redq[kp][0][jo4+3]=a03;
    redq[kp][1][jo4+0]=a10; redq[kp][1][jo4+1]=a11; redq[kp][1][jo4+2]=a12; redq[kp][1][jo4+3]=a13;
    __syncthreads();
    if (t < 128) {
      const int b = t >> 6, jo = t & 63;
      float s = 0.f;
#pragma unroll
      for (int k2 = 0; k2 < 16; ++k2) s += redq[k2][b][jo];
      qkv_part[(size_t)((ks * 3 + 0) * 2 + b) * D + jt * 64 + jo] = s;
    }
  } else {
    const int kv = bid - 256;
    const int mat = (kv >= 128) ? 2 : 1;
    const int r2 = kv & 127;
    const int ks = r2 >> 3, jt = r2 & 7;
    const int jo4 = (t & 31) * 4;
    const int kp = t >> 5;              // 0..7
    const int ib = ks * 64 + kp * 8;
    const float* W = (mat == 2) ? wv : wk;
    float4 wbuf[8];
#pragma unroll
    for (int r = 0; r < 8; ++r)
      wbuf[r] = *(const float4*)(W + (size_t)(ib + r) * D + jt * 128 + jo4);
    prologue_norm(hbase, has_prev ? down_part : nullptr, 16, scale, ln1, hn, nullptr);
    float a00=0,a01=0,a02=0,a03=0, a10=0,a11=0,a12=0,a13=0;
#pragma unroll
    for (int r = 0; r < 8; ++r) {
      const float x0 = hn[0][ib + r], x1 = hn[1][ib + r];
      a00 += wbuf[r].x*x0; a01 += wbuf[r].y*x0; a02 += wbuf[r].z*x0; a03 += wbuf[r].w*x0;
      a10 += wbuf[r].x*x1; a11 += wbuf[r].y*x1; a12 += wbuf[r].z*x1; a13 += wbuf[r].w*x1;
    }
    redkv[kp][0][jo4+0]=a00; redkv[kp][0][jo4+1]=a01; redkv[kp][0][jo4+2]=a02; redkv[kp][0][jo4+3]=a03;
    redkv[kp][1][jo4+0]=a10; redkv[kp][1][jo4+1]=a11; redkv[kp][1][jo4+2]=a12; redkv[kp][1][jo4+3]=a13;
    __syncthreads();
    {
      const int b = t >> 7, jo = t & 127;
      float s = 0.f;
#pragma unroll
      for (int k2 = 0; k2 < 8; ++k2) s += redkv[k2][b][jo];
      qkv_part[(size_t)((ks * 3 + mat) * 2 + b) * D + jt * 128 + jo] = s;
    }
  }
}

// ---------------------------------------------------------------------------
// Attention. grid(16, 32): 16 chunks x 32 keys; chunk 15 also handles the new
// token. Cache copy with nontemporal stores. Partials [m,l,acc64] stride 68.
// ---------------------------------------------------------------------------
__global__ __launch_bounds__(256) void k_attn(
    const float* __restrict__ qkv_part, const int* __restrict__ position,
    const float* __restrict__ k_in, const float* __restrict__ v_in,
    float* __restrict__ k_out, float* __restrict__ v_out,
    float* __restrict__ attn_part)
{
  const int t = threadIdx.x;
  const int chunk = blockIdx.x;   // 0..15
  const int bh = blockIdx.y;      // 0..31
  const int b = bh >> 4, h = bh & 15;
  const bool hasNew = (chunk == 15);
  __shared__ float q[64], kn[64], vn[64];
  __shared__ float sc[33];
  __shared__ float red8[8][32];
  __shared__ float pvred[16][64];
  __shared__ float msl[3];
  const size_t row_in  = (size_t)bh * S_CACHE;
  const size_t row_out = (size_t)bh * SP1;
  const int pbase = (bh * NCH + chunk) * 68;

  // coalesced cache copy (32 keys x 64 dims, K and V), NT stores
  {
    const v4f* ksrc = (const v4f*)(k_in + (row_in + chunk * 32) * 64);
    const v4f* vsrc = (const v4f*)(v_in + (row_in + chunk * 32) * 64);
    v4f* kdst = (v4f*)(k_out + (row_out + chunk * 32) * 64);
    v4f* vdst = (v4f*)(v_out + (row_out + chunk * 32) * 64);
    const v4f kc0 = ksrc[t], kc1 = ksrc[t + 256];
    const v4f vc0 = vsrc[t], vc1 = vsrc[t + 256];
    __builtin_nontemporal_store(kc0, &kdst[t]);
    __builtin_nontemporal_store(kc1, &kdst[t + 256]);
    __builtin_nontemporal_store(vc0, &vdst[t]);
    __builtin_nontemporal_store(vc1, &vdst[t + 256]);
  }
  // q combine (+ k/v combine for new token)
  if (t < 64) {
    float s = 0.f;
#pragma unroll
    for (int ks = 0; ks < 16; ++ks)
      s += qkv_part[(size_t)(ks * 6 + b) * D + h * 64 + t];
    q[t] = s;
  } else if (hasNew && t < 128) {
    const int u = t - 64;
    float s = 0.f;
#pragma unroll
    for (int ks = 0; ks < 16; ++ks)
      s += qkv_part[(size_t)(ks * 6 + 2 + b) * D + h * 64 + u];
    kn[u] = s;
  } else if (hasNew && t < 192) {
    const int u = t - 128;
    float s = 0.f;
#pragma unroll
    for (int ks = 0; ks < 16; ++ks)
      s += qkv_part[(size_t)(ks * 6 + 4 + b) * D + h * 64 + u];
    vn[u] = s;
  }
  __syncthreads();
  {
    const float pos = (float)position[b];
    if (t < 32) {
      const float inv = expf(-(float)t * 0.28782313662425575f);  // ln(1e4)/32
      const float ang = pos * inv;
      const float c = cosf(ang), sn = sinf(ang);
      const float x1 = q[t], x2 = q[t + 32];
      q[t]      = (x1 * c - x2 * sn) * 0.125f;
      q[t + 32] = (x1 * sn + x2 * c) * 0.125f;
    } else if (hasNew && t < 64) {
      const int u = t - 32;
      const float inv = expf(-(float)u * 0.28782313662425575f);
      const float ang = pos * inv;
      const float c = cosf(ang), sn = sinf(ang);
      const float x1 = kn[u], x2 = kn[u + 32];
      kn[u]      = x1 * c - x2 * sn;
      kn[u + 32] = x1 * sn + x2 * c;
    }
  }
  __syncthreads();
  if (hasNew && t < 64) {
    k_out[(row_out + S_CACHE) * 64 + t] = kn[t];
    v_out[(row_out + S_CACHE) * 64 + t] = vn[t];
    float dp = q[t] * kn[t];
#pragma unroll
    for (int off = 32; off; off >>= 1) dp += __shfl_xor(dp, off);
    if (t == 0) msl[0] = dp;
  }
  // scores over 32 old keys (k_in re-read hits L1 after the copy loads)
  {
    const int key = t & 31, kp = t >> 5;
    const float* krow = k_in + (row_in + chunk * 32 + key) * 64 + kp * 8;
    const float4 k0 = *(const float4*)krow;
    const float4 k1 = *(const float4*)(krow + 4);
    const int d = kp * 8;
    float dp = k0.x*q[d] + k0.y*q[d+1] + k0.z*q[d+2] + k0.w*q[d+3]
             + k1.x*q[d+4] + k1.y*q[d+5] + k1.z*q[d+6] + k1.w*q[d+7];
    red8[kp][key] = dp;
  }
  __syncthreads();
  if (t < 32) {
    float score = 0.f;
#pragma unroll
    for (int k2 = 0; k2 < 8; ++k2) score += red8[k2][t];
    float m = score;
#pragma unroll
    for (int off = 16; off; off >>= 1) m = fmaxf(m, __shfl_xor(m, off));
    const float nsc = hasNew ? msl[0] : -1e30f;
    m = fmaxf(m, nsc);
    const float p = expf(score - m);
    float l = p;
#pragma unroll
    for (int off = 16; off; off >>= 1) l += __shfl_xor(l, off);
    sc[t] = p;
    if (t == 0) {
      const float pn = hasNew ? expf(nsc - m) : 0.f;
      sc[32] = pn; msl[1] = m; msl[2] = l + pn;
    }
  }
  __syncthreads();
  {
    const int d4 = (t & 15) * 4, sp = t >> 4;
    float ax = 0.f, ay = 0.f, az = 0.f, aw = 0.f;
#pragma unroll
    for (int r = 0; r < 2; ++r) {
      const int sl = sp * 2 + r;
      const float4 vv = *(const float4*)(v_in + (row_in + chunk * 32 + sl) * 64 + d4);
      const float p2 = sc[sl];
      ax += vv.x * p2; ay += vv.y * p2; az += vv.z * p2; aw += vv.w * p2;
    }
    pvred[sp][d4+0]=ax; pvred[sp][d4+1]=ay; pvred[sp][d4+2]=az; pvred[sp][d4+3]=aw;
  }
  __syncthreads();
  if (t < 64) {
    float a = 0.f;
#pragma unroll
    for (int s2 = 0; s2 < 16; ++s2) a += pvred[s2][t];
    if (hasNew) a += sc[32] * vn[t];
    attn_part[pbase + 2 + t] = a;
    if (t == 0) { attn_part[pbase + 0] = msl[1]; attn_part[pbase + 1] = msl[2]; }
  }
}

// ---------------------------------------------------------------------------
// O-proj. grid(16, 32): ks = one head (64 rows), j-tile 32.
// Merges the 16 attention partials (softmax merge), then GEMV of wo.
// ---------------------------------------------------------------------------
__global__ __launch_bounds__(256) void k_oproj(
    const float* __restrict__ attn_part, const float* __restrict__ wo,
    float* __restrict__ oproj_part)
{
  __shared__ float o[2][64];
  __shared__ float cw[2][NCH];
  __shared__ float redg[32][2][32];
  __shared__ float redqq[4][2][32];
  const int t = threadIdx.x;
  const int ks = blockIdx.x;   // 0..15 (head)
  const int cg = blockIdx.y;   // 0..31
  const int ibeg = ks * 64;
  const int jbase = cg * 32;
  const int jo4 = (t & 7) * 4;
  const int kp = t >> 3;       // 0..31
  float4 wbuf[2];
#pragma unroll
  for (int r = 0; r < 2; ++r)
    wbuf[r] = *(const float4*)(wo + (size_t)(ibeg + kp * 2 + r) * D + jbase + jo4);
  if (t < 2) {
    const int bb = t;
    const int base = ((bb * 16 + ks) * NCH) * 68;
    float mg = -1e30f;
    for (int c = 0; c < NCH; ++c) mg = fmaxf(mg, attn_part[base + c * 68]);
    float lg = 0.f;
    float wloc[NCH];
    for (int c = 0; c < NCH; ++c) {
      const float w = expf(attn_part[base + c * 68] - mg);
      wloc[c] = w;
      lg += attn_part[base + c * 68 + 1] * w;
    }
    const float invl = 1.f / lg;
    for (int c = 0; c < NCH; ++c) cw[bb][c] = wloc[c] * invl;
  }
  __syncthreads();
  if (t < 128) {
    const int bb = t >> 6, d = t & 63;
    float s = 0.f;
#pragma unroll
    for (int c = 0; c < NCH; ++c)
      s += attn_part[((bb * 16 + ks) * NCH + c) * 68 + 2 + d] * cw[bb][c];
    o[bb][d] = s;
  }
  __syncthreads();
  float a00=0,a01=0,a02=0,a03=0, a10=0,a11=0,a12=0,a13=0;
#pragma unroll
  for (int r = 0; r < 2; ++r) {
    const int ir = kp * 2 + r;
    const float x0 = o[0][ir], x1 = o[1][ir];
    a00 += wbuf[r].x*x0; a01 += wbuf[r].y*x0; a02 += wbuf[r].z*x0; a03 += wbuf[r].w*x0;
    a10 += wbuf[r].x*x1; a11 += wbuf[r].y*x1; a12 += wbuf[r].z*x1; a13 += wbuf[r].w*x1;
  }
  redg[kp][0][jo4+0]=a00; redg[kp][0][jo4+1]=a01; redg[kp][0][jo4+2]=a02; redg[kp][0][jo4+3]=a03;
  redg[kp][1][jo4+0]=a10; redg[kp][1][jo4+1]=a11; redg[kp][1][jo4+2]=a12; redg[kp][1][jo4+3]=a13;
  __syncthreads();
  {
    const int qq = t >> 6, rest = t & 63;
    const int b2 = rest >> 5, jo = rest & 31;
    float s = 0.f;
#pragma unroll
    for (int k2 = 0; k2 < 8; ++k2) s += redg[qq * 8 + k2][b2][jo];
    redqq[qq][b2][jo] = s;
  }
  __syncthreads();
  if (t < 64) {
    const int b2 = t >> 5, jo = t & 31;
    const float s = redqq[0][b2][jo] + redqq[1][b2][jo] + redqq[2][b2][jo] + redqq[3][b2][jo];
    oproj_part[(size_t)(ks * 2 + b2) * D + jbase + jo] = s;
  }
}

// ---------------------------------------------------------------------------
// Gate+Up GEMV. grid(8, 64): ks = 128-row K-range, j-tile 64. Prologue
// combines 16 oproj partials + residual + rmsnorm; block 0 writes raw h2.
// ---------------------------------------------------------------------------
__global__ __launch_bounds__(256) void k_gateup(
    const float* __restrict__ hbase, const float* __restrict__ oproj_part,
    float* __restrict__ h2_out, const float* __restrict__ ln2,
    const float* __restrict__ wg, const float* __restrict__ wu,
    float* __restrict__ gu_part, float scale)
{
  __shared__ float hn[2][D];
  __shared__ float redg[16][4][64];
  const int t = threadIdx.x;
  const int ks = blockIdx.x;   // 0..7
  const int cg = blockIdx.y;   // 0..63
  const int jbase = cg * 64;
  const int jo4 = (t & 15) * 4;
  const int kp = t >> 4;
  const int ib = ks * 128 + kp * 8;
  float4 wgb[8];
#pragma unroll
  for (int r = 0; r < 8; ++r)
    wgb[r] = *(const float4*)(wg + (size_t)(ib + r) * DFF + jbase + jo4);
  prologue_norm(hbase, oproj_part, 16, scale, ln2, hn, h2_out);
  float g00=0,g01=0,g02=0,g03=0, g10=0,g11=0,g12=0,g13=0;
  float u00=0,u01=0,u02=0,u03=0, u10=0,u11=0,u12=0,u13=0;
#pragma unroll
  for (int r = 0; r < 8; ++r) {
    const float x0 = hn[0][ib + r], x1 = hn[1][ib + r];
    g00 += wgb[r].x*x0; g01 += wgb[r].y*x0; g02 += wgb[r].z*x0; g03 += wgb[r].w*x0;
    g10 += wgb[r].x*x1; g11 += wgb[r].y*x1; g12 += wgb[r].z*x1; g13 += wgb[r].w*x1;
  }
#pragma unroll
  for (int r = 0; r < 8; ++r) {
    const float4 c = *(const float4*)(wu + (size_t)(ib + r) * DFF + jbase + jo4);
    const float x0 = hn[0][ib + r], x1 = hn[1][ib + r];
    u00 += c.x*x0; u01 += c.y*x0; u02 += c.z*x0; u03 += c.w*x0;
    u10 += c.x*x1; u11 += c.y*x1; u12 += c.z*x1; u13 += c.w*x1;
  }
  redg[kp][0][jo4+0]=g00; redg[kp][0][jo4+1]=g01; redg[kp][0][jo4+2]=g02; redg[kp][0][jo4+3]=g03;
  redg[kp][1][jo4+0]=g10; redg[kp][1][jo4+1]=g11; redg[kp][1][jo4+2]=g12; redg[kp][1][jo4+3]=g13;
  redg[kp][2][jo4+0]=u00; redg[kp][2][jo4+1]=u01; redg[kp][2][jo4+2]=u02; redg[kp][2][jo4+3]=u03;
  redg[kp][3][jo4+0]=u10; redg[kp][3][jo4+1]=u11; redg[kp][3][jo4+2]=u12; redg[kp][3][jo4+3]=u13;
  __syncthreads();
  {
    const int sel = t >> 6;      // 0:g,b0 1:g,b1 2:u,b0 3:u,b1
    const int jo = t & 63;
    float s = 0.f;
#pragma unroll
    for (int k2 = 0; k2 < 16; ++k2) s += redg[k2][sel][jo];
    const int gm = sel >> 1, b = sel & 1;
    gu_part[(size_t)(ks * 4 + gm * 2 + b) * DFF + jbase + jo] = s;
  }
}

// ---------------------------------------------------------------------------
// Down GEMV. grid(16, 32): ks = 256-row K-range of DFF, j-tile 32.
// act = silu(g)*u combined from 8 gu splits.
// ---------------------------------------------------------------------------
__global__ __launch_bounds__(256) void k_down(
    const float* __restrict__ gu_part, const float* __restrict__ wd,
    float* __restrict__ down_part)
{
  __shared__ float act[2][256];
  __shared__ float redg[32][2][32];
  __shared__ float redqq[4][2][32];
  const int t = threadIdx.x;
  const int ks = blockIdx.x;   // 0..15
  const int cg = blockIdx.y;   // 0..31
  const int ibeg = ks * 256;
  const int jbase = cg * 32;
  const int jo4 = (t & 7) * 4;
  const int kp = t >> 3;       // 0..31
  float4 wbuf[8];
#pragma unroll
  for (int r = 0; r < 8; ++r)
    wbuf[r] = *(const float4*)(wd + (size_t)(ibeg + kp * 8 + r) * D + jbase + jo4);
#pragma unroll
  for (int u = 0; u < 2; ++u) {
    const int e = u * 256 + t;
    const int b = e >> 8, ir = e & 255;
    const int i = ibeg + ir;
    float g = 0.f, uu = 0.f;
#pragma unroll
    for (int k = 0; k < 8; ++k) {
      g  += gu_part[(size_t)(k * 4 + b) * DFF + i];
      uu += gu_part[(size_t)(k * 4 + 2 + b) * DFF + i];
    }
    act[b][ir] = silu_f(g) * uu;
  }
  __syncthreads();
  float a00=0,a01=0,a02=0,a03=0, a10=0,a11=0,a12=0,a13=0;
#pragma unroll
  for (int r = 0; r < 8; ++r) {
    const int lr = kp * 8 + r;
    const float x0 = act[0][lr], x1 = act[1][lr];
    a00 += wbuf[r].x*x0; a01 += wbuf[r].y*x0; a02 += wbuf[r].z*x0; a03 += wbuf[r].w*x0;
    a10 += wbuf[r].x*x1; a11 += wbuf[r].y*x1; a12 += wbuf[r].z*x1; a13 += wbuf[r].w*x1;
  }
  redg[kp][0][jo4+0]=a00; redg[kp][0][jo4+1]=a01; redg[kp][0][jo4+2]=a02; redg[kp][0][jo4+3]=a03;
  redg[kp][1][jo4+0]=a10; redg[kp][1][jo4+1]=a11; redg[kp][1][jo4+2]=a12; redg[kp][1][jo4+3]=a13;
  __syncthreads();
  {
    const int qq = t >> 6, rest = t & 63;
    const int b2 = rest >> 5, jo = rest & 31;
    float s = 0.f;
#pragma unroll
    for (int k2 = 0; k2 < 8; ++k2) s += redg[qq * 8 + k2][b2][jo];
    redqq[qq][b2][jo] = s;
  }
  __syncthreads();
  if (t < 64) {
    const int b2 = t >> 5, jo = t & 31;
    const float s = redqq[0][b2][jo] + redqq[1][b2][jo] + redqq[2][b2][jo] + redqq[3][b2][jo];
    down_part[(size_t)(ks * 2 + b2) * D + jbase + jo] = s;
  }
}

// ---------------------------------------------------------------------------
// Fused heads: blocks 0..127 stop-proj GEMV; blocks 128..143 FSQ head.
// Both start from lm_hidden = rmsnorm(h2 + scale*down, base_norm).
// ---------------------------------------------------------------------------
__global__ __launch_bounds__(256) void k_heads(
    const float* __restrict__ hbase, const float* __restrict__ down_part,
    const float* __restrict__ normw, const float* __restrict__ wsp,
    float* __restrict__ sproj_part,
    const float* __restrict__ fsq_in, const float* __restrict__ fsq_out,
    const float* __restrict__ embed,
    float* __restrict__ out_fsq, float* __restrict__ h_res, float scale)
{
  __shared__ float hn[2][D];
  const int t = threadIdx.x;
  const int bid = blockIdx.x;
  if (bid < 128) {
    __shared__ float redg[16][2][64];
    const int ks = bid >> 4, cg = bid & 15;
    const int jbase = cg * 64;
    const int jo4 = (t & 15) * 4;
    const int kp = t >> 4;
    const int ib = ks * 128 + kp * 8;
    float4 wbuf[8];
#pragma unroll
    for (int r = 0; r < 8; ++r)
      wbuf[r] = *(const float4*)(wsp + (size_t)(ib + r) * D + jbase + jo4);
    prologue_norm(hbase, down_part, 16, scale, normw, hn, nullptr);
    float a00=0,a01=0,a02=0,a03=0, a10=0,a11=0,a12=0,a13=0;
#pragma unroll
    for (int r = 0; r < 8; ++r) {
      const float x0 = hn[0][ib + r], x1 = hn[1][ib + r];
      a00 += wbuf[r].x*x0; a01 += wbuf[r].y*x0; a02 += wbuf[r].z*x0; a03 += wbuf[r].w*x0;
      a10 += wbuf[r].x*x1; a11 += wbuf[r].y*x1; a12 += wbuf[r].z*x1; a13 += wbuf[r].w*x1;
    }
    redg[kp][0][jo4+0]=a00; redg[kp][0][jo4+1]=a01; redg[kp][0][jo4+2]=a02; redg[kp][0][jo4+3]=a03;
    redg[kp][1][jo4+0]=a10; redg[kp][1][jo4+1]=a11; redg[kp][1][jo4+2]=a12; redg[kp][1][jo4+3]=a13;
    __syncthreads();
    if (t < 128) {
      const int b = t >> 6, jo = t & 63;
      float s = 0.f;
#pragma unroll
      for (int k2 = 0; k2 < 16; ++k2) s += redg[k2][b][jo];
      sproj_part[(size_t)(ks * 2 + b) * D + jbase + jo] = s;
    }
  } else {
    __shared__ float zred[4][2][32];
    __shared__ float zq[2][32];
    prologue_norm(hbase, down_part, 16, scale, normw, hn, nullptr);
    {
      const int c = t & 31, b = (t >> 5) & 1, kp = t >> 6;
      float s = 0.f;
      for (int i = kp * 256; i < kp * 256 + 256; ++i) s += hn[b][i] * fsq_in[i * 32 + c];
      zred[kp][b][c] = s;
    }
    __syncthreads();
    if (t < 64) {
      const int b = t >> 5, c = t & 31;
      float z = zred[0][b][c] + zred[1][b][c] + zred[2][b][c] + zred[3][b][c];
      z = tanhf(z);
      zq[b][c] = rintf(z * 3.5f) / 3.5f;
    }
    __syncthreads();
    if (t < 128) {
      const int b = t >> 6, jo = t & 63;
      const int j = (bid - 128) * 64 + jo;
      float s = 0.f;
#pragma unroll
      for (int c = 0; c < 32; ++c) s += zq[b][c] * fsq_out[c * D + j];
      out_fsq[b * D + j] = s;
      h_res[b * D + j] = s + embed[b * D + j];
    }
  }
}

// ---------------------------------------------------------------------------
__global__ __launch_bounds__(256) void k_stophead(
    const float* __restrict__ sproj_part, const float* __restrict__ bvec,
    const float* __restrict__ hw, const float* __restrict__ hb,
    float* __restrict__ out_stop)
{
  const int t = threadIdx.x;
  float acc0 = 0.f, acc1 = 0.f;
  for (int j = t; j < D; j += 256) {
    float v0 = bvec[j], v1 = bvec[j];
#pragma unroll
    for (int ks = 0; ks < 8; ++ks) {
      v0 += sproj_part[(ks * 2 + 0) * D + j];
      v1 += sproj_part[(ks * 2 + 1) * D + j];
    }
    acc0 += silu_f(v0) * hw[j];
    acc1 += silu_f(v1) * hw[j];
  }
  __shared__ float red[256];
  red[t] = acc0;
  __syncthreads();
  for (int s = 128; s > 0; s >>= 1) { if (t < s) red[t] += red[t + s]; __syncthreads(); }
  if (t == 0) out_stop[0] = red[0] + hb[0];
  __syncthreads();
  red[t] = acc1;
  __syncthreads();
  for (int s = 128; s > 0; s >>= 1) { if (t < s) red[t] += red[t + s]; __syncthreads(); }
  if (t == 0) out_stop[1] = red[0] + hb[0];
}

// ---------------------------------------------------------------------------
__global__ __launch_bounds__(256) void k_final(
    const float* __restrict__ hbase, const float* __restrict__ down_part,
    const float* __restrict__ normw, float* __restrict__ out_rh, float scale)
{
  __shared__ float hn[2][D];
  prologue_norm(hbase, down_part, 16, scale, normw, hn, nullptr);
  const int t = threadIdx.x;
  const int b = t >> 7;
  const int i0 = (t & 127) * 8;
#pragma unroll
  for (int u = 0; u < 8; ++u) out_rh[b * D + i0 + u] = hn[b][i0 + u];
}

// ---------------------------------------------------------------------------
extern "C" void kernel_launch(void* const* d_in, const int* in_sizes, int n_in,
                              void* d_out, int out_size, void* d_ws, size_t ws_size,
                              hipStream_t stream) {
  const float* embed      = (const float*)d_in[0];
  const int*   position   = (const int*)d_in[1];
  const float* base_k     = (const float*)d_in[2];
  const float* base_v     = (const float*)d_in[3];
  const float* res_k      = (const float*)d_in[4];
  const float* res_v      = (const float*)d_in[5];
  const float* base_ln1   = (const float*)d_in[6];
  const float* base_ln2   = (const float*)d_in[7];
  const float* base_wq    = (const float*)d_in[8];
  const float* base_wk    = (const float*)d_in[9];
  const float* base_wv    = (const float*)d_in[10];
  const float* base_wo    = (const float*)d_in[11];
  const float* base_wg    = (const float*)d_in[12];
  const float* base_wu    = (const float*)d_in[13];
  const float* base_wd    = (const float*)d_in[14];
  const float* base_norm  = (const float*)d_in[15];
  const float* res_ln1    = (const float*)d_in[16];
  const float* res_ln2    = (const float*)d_in[17];
  const float* res_wq     = (const float*)d_in[18];
  const float* res_wk     = (const float*)d_in[19];
  const float* res_wv     = (const float*)d_in[20];
  const float* res_wo     = (const float*)d_in[21];
  const float* res_wg     = (const float*)d_in[22];
  const float* res_wu     = (const float*)d_in[23];
  const float* res_wd     = (const float*)d_in[24];
  const float* res_norm   = (const float*)d_in[25];
  const float* fsq_in     = (const float*)d_in[26];
  const float* fsq_out    = (const float*)d_in[27];
  const float* stop_proj_w = (const float*)d_in[28];
  const float* stop_proj_b = (const float*)d_in[29];
  const float* stop_head_w = (const float*)d_in[30];
  const float* stop_head_b = (const float*)d_in[31];

  float* out = (float*)d_out;
  float* ws = (float*)d_ws;
  float* W_h     = ws + WS_H;
  float* W_h2    = ws + WS_H2;
  float* W_qkv   = ws + WS_QKV;
  float* W_attn  = ws + WS_ATTN;
  float* W_oproj = ws + WS_OPROJ;
  float* W_gu    = ws + WS_GU;
  float* W_down  = ws + WS_DOWN;
  float* W_sproj = ws + WS_SPROJ;

  const size_t cacheL_in  = (size_t)2 * NHEADS * S_CACHE * DH;   // 1048576
  const size_t cacheL_out = (size_t)2 * NHEADS * SP1 * DH;       // 1050624
  float* out_fsq  = out;
  float* out_rh   = out + 2048;
  float* out_stop = out + 4096;
  float* out_bnk  = out + 4098;
  float* out_bnv  = out_bnk + (size_t)NB_L * cacheL_out;
  float* out_rnk  = out_bnv + (size_t)NB_L * cacheL_out;
  float* out_rnv  = out_rnk + (size_t)NR_L * cacheL_out;

  const float scaleB = 1.4f / sqrtf((float)NB_L);
  const float scaleR = 1.4f / sqrtf((float)NR_L);

  auto run_layer = [&](const float* hbase, float* hout,
                       const float* ln1, const float* ln2,
                       const float* wq, const float* wk, const float* wv,
                       const float* wo, const float* wg, const float* wu,
                       const float* wd,
                       const float* kin, const float* vin,
                       float* kout, float* vout,
                       float scale, int has_prev) {
    k_qkv<<<512, 256, 0, stream>>>(hbase, W_down, hout, ln1,
                                   wq, wk, wv, W_qkv, scale, has_prev);
    k_attn<<<dim3(NCH, 32), 256, 0, stream>>>(W_qkv, position, kin, vin, kout, vout, W_attn);
    k_oproj<<<dim3(16, 32), 256, 0, stream>>>(W_attn, wo, W_oproj);
    k_gateup<<<dim3(8, 64), 256, 0, stream>>>(W_h, W_oproj, W_h2, ln2, wg, wu, W_gu, scale);
    k_down<<<dim3(16, 32), 256, 0, stream>>>(W_gu, wd, W_down);
  };

  for (int l = 0; l < NB_L; ++l) {
    run_layer(l == 0 ? embed : W_h2, W_h,
              base_ln1 + (size_t)l * D, base_ln2 + (size_t)l * D,
              base_wq + (size_t)l * D * D, base_wk + (size_t)l * D * D,
              base_wv + (size_t)l * D * D, base_wo + (size_t)l * D * D,
              base_wg + (size_t)l * D * DFF, base_wu + (size_t)l * D * DFF,
              base_wd + (size_t)l * DFF * D,
              base_k + (size_t)l * cacheL_in, base_v + (size_t)l * cacheL_in,
              out_bnk + (size_t)l * cacheL_out, out_bnv + (size_t)l * cacheL_out,
              scaleB, l > 0);
  }

  k_heads<<<144, 256, 0, stream>>>(W_h2, W_down, base_norm, stop_proj_w, W_sproj,
                                   fsq_in, fsq_out, embed, out_fsq, W_h, scaleB);
  k_stophead<<<1, 256, 0, stream>>>(W_sproj, stop_proj_b, stop_head_w, stop_head_b, out_stop);

  for (int l = 0; l < NR_L; ++l) {
    run_layer(l == 0 ? W_h : W_h2, l == 0 ? nullptr : W_h,
              res_ln1 + (size_t)l * D, res_ln2 + (size_t)l * D,
              res_wq + (size_t)l * D * D, res_wk + (size_t)l * D * D,
              res_wv + (size_t)l * D * D, res_wo + (size_t)l * D * D,
              res_wg + (size_t)l * D * DFF, res_wu + (size_t)l * D * DFF,
              res_wd + (size_t)l * DFF * D,
              res_k + (size_t)l * cacheL_in, res_v + (size_t)l * cacheL_in,
              out_rnk + (size_t)l * cacheL_out, out_rnv + (size_t)l * cacheL_out,
              scaleR, l > 0);
  }

  k_final<<<1, 256, 0, stream>>>(W_h2, W_down, res_norm, out_rh, scaleR);
}

// Round 9
// 1151.753 us; speedup vs baseline: 1.0252x; 1.0252x over previous
//
#include <hip/hip_runtime.h>
#include <cmath>

#define D 1024
#define DFF 4096
#define NHEADS 16
#define DH 64
#define S_CACHE 512
#define SP1 513
#define NB_L 24
#define NR_L 8
#define NCH 16

typedef float v4f __attribute__((ext_vector_type(4)));

// workspace layout (float offsets)
#define WS_H      0         // [2][1024]
#define WS_H2     2048      // [2][1024]
#define WS_QKV    4096      // [16][3][2][1024] = 98304
#define WS_ATTN   102400    // [32][16][68]     = 34816
#define WS_OPROJ  137216    // [8][2][1024]     = 16384
#define WS_GU     153600    // [8][2][2][4096]  = 131072
#define WS_DOWN   284672    // [8][2][1024]     = 16384
#define WS_SPROJ  301056    // [8][2][1024]     = 16384

__device__ __forceinline__ float silu_f(float x){ return x/(1.f+expf(-x)); }

// ---------------------------------------------------------------------------
// prologue: h = hbase (+ scale * sum_ks part) -> rmsnorm(lnw) -> hn (LDS).
// Wave-shuffle reduction: 2 barriers. block 0 optionally writes raw h.
// ---------------------------------------------------------------------------
__device__ __forceinline__ void prologue_norm(
    const float* __restrict__ hbase,
    const float* __restrict__ part, int nks, float scale,
    const float* __restrict__ lnw,
    float (*hn)[D], float* __restrict__ hout)
{
  __shared__ float redw[4];
  const int t = threadIdx.x;
  const int b = t >> 7;
  const int i0 = (t & 127) * 8;
  const float4* hb4 = (const float4*)(hbase + b * D + i0);
  const float4 h0 = hb4[0], h1 = hb4[1];
  float acc[8] = {h0.x, h0.y, h0.z, h0.w, h1.x, h1.y, h1.z, h1.w};
  if (part != nullptr) {
    float s[8] = {0,0,0,0,0,0,0,0};
    for (int ks = 0; ks < nks; ++ks) {
      const float4* p4 = (const float4*)(part + (size_t)(ks * 2 + b) * D + i0);
      const float4 a = p4[0], c = p4[1];
      s[0]+=a.x; s[1]+=a.y; s[2]+=a.z; s[3]+=a.w;
      s[4]+=c.x; s[5]+=c.y; s[6]+=c.z; s[7]+=c.w;
    }
#pragma unroll
    for (int u = 0; u < 8; ++u) acc[u] += scale * s[u];
  }
  float ssq = 0.f;
#pragma unroll
  for (int u = 0; u < 8; ++u) ssq += acc[u] * acc[u];
#pragma unroll
  for (int off = 32; off; off >>= 1) ssq += __shfl_xor(ssq, off);
  if ((t & 63) == 0) redw[t >> 6] = ssq;
  __syncthreads();
  const float r = rsqrtf((redw[b * 2] + redw[b * 2 + 1]) * (1.f / D) + 1e-5f);
#pragma unroll
  for (int u = 0; u < 8; ++u) hn[b][i0 + u] = acc[u] * r * lnw[i0 + u];
  if (hout != nullptr && blockIdx.x == 0 && blockIdx.y == 0) {
    float4* o4 = (float4*)(hout + b * D + i0);
    o4[0] = make_float4(acc[0], acc[1], acc[2], acc[3]);
    o4[1] = make_float4(acc[4], acc[5], acc[6], acc[7]);
  }
  __syncthreads();
}

// ---------------------------------------------------------------------------
// QKV GEMV. grid(512): blocks 0..255 Q (16 ks x 16 j-tiles of 64 cols);
// blocks 256..511 K/V (16 ks x 8 j-tiles of 128 cols each).
// Weight tile fully preloaded into regs before prologue.
// ---------------------------------------------------------------------------
__global__ __launch_bounds__(256) void k_qkv(
    const float* __restrict__ hbase, const float* __restrict__ down_part,
    float* __restrict__ hout, const float* __restrict__ ln1,
    const float* __restrict__ wq, const float* __restrict__ wk,
    const float* __restrict__ wv,
    float* __restrict__ qkv_part, float scale, int has_prev)
{
  __shared__ float hn[2][D];
  __shared__ float redq[16][2][64];
  __shared__ float redkv[8][2][128];
  const int t = threadIdx.x;
  const int bid = blockIdx.x;
  if (bid < 256) {
    const int ks = bid >> 4, jt = bid & 15;
    const int jo4 = (t & 15) * 4;
    const int kp = t >> 4;              // 0..15
    const int ib = ks * 64 + kp * 4;
    float4 wbuf[4];
#pragma unroll
    for (int r = 0; r < 4; ++r)
      wbuf[r] = *(const float4*)(wq + (size_t)(ib + r) * D + jt * 64 + jo4);
    prologue_norm(hbase, has_prev ? down_part : nullptr, 8, scale, ln1, hn, hout);
    float a00=0,a01=0,a02=0,a03=0, a10=0,a11=0,a12=0,a13=0;
#pragma unroll
    for (int r = 0; r < 4; ++r) {
      const float x0 = hn[0][ib + r], x1 = hn[1][ib + r];
      a00 += wbuf[r].x*x0; a01 += wbuf[r].y*x0; a02 += wbuf[r].z*x0; a03 += wbuf[r].w*x0;
      a10 += wbuf[r].x*x1; a11 += wbuf[r].y*x1; a12 += wbuf[r].z*x1; a13 += wbuf[r].w*x1;
    }
    redq[kp][0][jo4+0]=a00; redq[kp][0][jo4+1]=a01; redq[kp][0][jo4+2]=a02; redq[kp][0][jo4+3]=a03;
    redq[kp][1][jo4+0]=a10; redq[kp][1][jo4+1]=a11; redq[kp][1][jo4+2]=a12; redq[kp][1][jo4+3]=a13;
    __syncthreads();
    if (t < 128) {
      const int b = t >> 6, jo = t & 63;
      float s = 0.f;
#pragma unroll
      for (int k2 = 0; k2 < 16; ++k2) s += redq[k2][b][jo];
      qkv_part[(size_t)((ks * 3 + 0) * 2 + b) * D + jt * 64 + jo] = s;
    }
  } else {
    const int kv = bid - 256;
    const int mat = (kv >= 128) ? 2 : 1;
    const int r2 = kv & 127;
    const int ks = r2 >> 3, jt = r2 & 7;
    const int jo4 = (t & 31) * 4;
    const int kp = t >> 5;              // 0..7
    const int ib = ks * 64 + kp * 8;
    const float* W = (mat == 2) ? wv : wk;
    float4 wbuf[8];
#pragma unroll
    for (int r = 0; r < 8; ++r)
      wbuf[r] = *(const float4*)(W + (size_t)(ib + r) * D + jt * 128 + jo4);
    prologue_norm(hbase, has_prev ? down_part : nullptr, 8, scale, ln1, hn, nullptr);
    float a00=0,a01=0,a02=0,a03=0, a10=0,a11=0,a12=0,a13=0;
#pragma unroll
    for (int r = 0; r < 8; ++r) {
      const float x0 = hn[0][ib + r], x1 = hn[1][ib + r];
      a00 += wbuf[r].x*x0; a01 += wbuf[r].y*x0; a02 += wbuf[r].z*x0; a03 += wbuf[r].w*x0;
      a10 += wbuf[r].x*x1; a11 += wbuf[r].y*x1; a12 += wbuf[r].z*x1; a13 += wbuf[r].w*x1;
    }
    redkv[kp][0][jo4+0]=a00; redkv[kp][0][jo4+1]=a01; redkv[kp][0][jo4+2]=a02; redkv[kp][0][jo4+3]=a03;
    redkv[kp][1][jo4+0]=a10; redkv[kp][1][jo4+1]=a11; redkv[kp][1][jo4+2]=a12; redkv[kp][1][jo4+3]=a13;
    __syncthreads();
    {
      const int b = t >> 7, jo = t & 127;
      float s = 0.f;
#pragma unroll
      for (int k2 = 0; k2 < 8; ++k2) s += redkv[k2][b][jo];
      qkv_part[(size_t)((ks * 3 + mat) * 2 + b) * D + jt * 128 + jo] = s;
    }
  }
}

// ---------------------------------------------------------------------------
// Attention. grid(16, 32): 16 chunks x 32 keys; chunk 15 also handles the new
// token. Cache copy with nontemporal stores. Partials [m,l,acc64] stride 68.
// ---------------------------------------------------------------------------
__global__ __launch_bounds__(256) void k_attn(
    const float* __restrict__ qkv_part, const int* __restrict__ position,
    const float* __restrict__ k_in, const float* __restrict__ v_in,
    float* __restrict__ k_out, float* __restrict__ v_out,
    float* __restrict__ attn_part)
{
  const int t = threadIdx.x;
  const int chunk = blockIdx.x;   // 0..15
  const int bh = blockIdx.y;      // 0..31
  const int b = bh >> 4, h = bh & 15;
  const bool hasNew = (chunk == 15);
  __shared__ float q[64], kn[64], vn[64];
  __shared__ float sc[33];
  __shared__ float red8[8][32];
  __shared__ float pvred[16][64];
  __shared__ float msl[3];
  const size_t row_in  = (size_t)bh * S_CACHE;
  const size_t row_out = (size_t)bh * SP1;
  const int pbase = (bh * NCH + chunk) * 68;

  // coalesced cache copy (32 keys x 64 dims, K and V), NT stores
  {
    const v4f* ksrc = (const v4f*)(k_in + (row_in + chunk * 32) * 64);
    const v4f* vsrc = (const v4f*)(v_in + (row_in + chunk * 32) * 64);
    v4f* kdst = (v4f*)(k_out + (row_out + chunk * 32) * 64);
    v4f* vdst = (v4f*)(v_out + (row_out + chunk * 32) * 64);
    const v4f kc0 = ksrc[t], kc1 = ksrc[t + 256];
    const v4f vc0 = vsrc[t], vc1 = vsrc[t + 256];
    __builtin_nontemporal_store(kc0, &kdst[t]);
    __builtin_nontemporal_store(kc1, &kdst[t + 256]);
    __builtin_nontemporal_store(vc0, &vdst[t]);
    __builtin_nontemporal_store(vc1, &vdst[t + 256]);
  }
  // q combine (+ k/v combine for new token)
  if (t < 64) {
    float s = 0.f;
#pragma unroll
    for (int ks = 0; ks < 16; ++ks)
      s += qkv_part[(size_t)(ks * 6 + b) * D + h * 64 + t];
    q[t] = s;
  } else if (hasNew && t < 128) {
    const int u = t - 64;
    float s = 0.f;
#pragma unroll
    for (int ks = 0; ks < 16; ++ks)
      s += qkv_part[(size_t)(ks * 6 + 2 + b) * D + h * 64 + u];
    kn[u] = s;
  } else if (hasNew && t < 192) {
    const int u = t - 128;
    float s = 0.f;
#pragma unroll
    for (int ks = 0; ks < 16; ++ks)
      s += qkv_part[(size_t)(ks * 6 + 4 + b) * D + h * 64 + u];
    vn[u] = s;
  }
  __syncthreads();
  {
    const float pos = (float)position[b];
    if (t < 32) {
      const float inv = expf(-(float)t * 0.28782313662425575f);  // ln(1e4)/32
      const float ang = pos * inv;
      const float c = cosf(ang), sn = sinf(ang);
      const float x1 = q[t], x2 = q[t + 32];
      q[t]      = (x1 * c - x2 * sn) * 0.125f;
      q[t + 32] = (x1 * sn + x2 * c) * 0.125f;
    } else if (hasNew && t < 64) {
      const int u = t - 32;
      const float inv = expf(-(float)u * 0.28782313662425575f);
      const float ang = pos * inv;
      const float c = cosf(ang), sn = sinf(ang);
      const float x1 = kn[u], x2 = kn[u + 32];
      kn[u]      = x1 * c - x2 * sn;
      kn[u + 32] = x1 * sn + x2 * c;
    }
  }
  __syncthreads();
  if (hasNew && t < 64) {
    k_out[(row_out + S_CACHE) * 64 + t] = kn[t];
    v_out[(row_out + S_CACHE) * 64 + t] = vn[t];
    float dp = q[t] * kn[t];
#pragma unroll
    for (int off = 32; off; off >>= 1) dp += __shfl_xor(dp, off);
    if (t == 0) msl[0] = dp;
  }
  // scores over 32 old keys (k_in re-read hits L1 after the copy loads)
  {
    const int key = t & 31, kp = t >> 5;
    const float* krow = k_in + (row_in + chunk * 32 + key) * 64 + kp * 8;
    const float4 k0 = *(const float4*)krow;
    const float4 k1 = *(const float4*)(krow + 4);
    const int d = kp * 8;
    float dp = k0.x*q[d] + k0.y*q[d+1] + k0.z*q[d+2] + k0.w*q[d+3]
             + k1.x*q[d+4] + k1.y*q[d+5] + k1.z*q[d+6] + k1.w*q[d+7];
    red8[kp][key] = dp;
  }
  __syncthreads();
  if (t < 32) {
    float score = 0.f;
#pragma unroll
    for (int k2 = 0; k2 < 8; ++k2) score += red8[k2][t];
    float m = score;
#pragma unroll
    for (int off = 16; off; off >>= 1) m = fmaxf(m, __shfl_xor(m, off));
    const float nsc = hasNew ? msl[0] : -1e30f;
    m = fmaxf(m, nsc);
    const float p = expf(score - m);
    float l = p;
#pragma unroll
    for (int off = 16; off; off >>= 1) l += __shfl_xor(l, off);
    sc[t] = p;
    if (t == 0) {
      const float pn = hasNew ? expf(nsc - m) : 0.f;
      sc[32] = pn; msl[1] = m; msl[2] = l + pn;
    }
  }
  __syncthreads();
  {
    const int d4 = (t & 15) * 4, sp = t >> 4;
    float ax = 0.f, ay = 0.f, az = 0.f, aw = 0.f;
#pragma unroll
    for (int r = 0; r < 2; ++r) {
      const int sl = sp * 2 + r;
      const float4 vv = *(const float4*)(v_in + (row_in + chunk * 32 + sl) * 64 + d4);
      const float p2 = sc[sl];
      ax += vv.x * p2; ay += vv.y * p2; az += vv.z * p2; aw += vv.w * p2;
    }
    pvred[sp][d4+0]=ax; pvred[sp][d4+1]=ay; pvred[sp][d4+2]=az; pvred[sp][d4+3]=aw;
  }
  __syncthreads();
  if (t < 64) {
    float a = 0.f;
#pragma unroll
    for (int s2 = 0; s2 < 16; ++s2) a += pvred[s2][t];
    if (hasNew) a += sc[32] * vn[t];
    attn_part[pbase + 2 + t] = a;
    if (t == 0) { attn_part[pbase + 0] = msl[1]; attn_part[pbase + 1] = msl[2]; }
  }
}

// ---------------------------------------------------------------------------
// O-proj. grid(8, 64): ks = 128-row K-range (2 heads), j-tile 16.
// Merges the 16 attention partials (softmax merge), then GEMV of wo.
// 8 K-partials out. Full weight prefetch.
// ---------------------------------------------------------------------------
__global__ __launch_bounds__(256) void k_oproj(
    const float* __restrict__ attn_part, const float* __restrict__ wo,
    float* __restrict__ oproj_part)
{
  __shared__ float o[2][128];
  __shared__ float cw[4][NCH];
  __shared__ float redg[64][2][16];
  __shared__ float redq2[8][2][16];
  const int t = threadIdx.x;
  const int ks = blockIdx.x;   // 0..7 (2 heads)
  const int jt = blockIdx.y;   // 0..63
  const int ibeg = ks * 128;
  const int jbase = jt * 16;
  const int jo4 = (t & 3) * 4;
  const int kp = t >> 2;       // 0..63, 2 rows each
  float4 wbuf[2];
#pragma unroll
  for (int r = 0; r < 2; ++r)
    wbuf[r] = *(const float4*)(wo + (size_t)(ibeg + kp * 2 + r) * D + jbase + jo4);
  if (t < 4) {
    const int bb = t >> 1, hr = t & 1;
    const int hh = ks * 2 + hr;
    const int base = ((bb * 16 + hh) * NCH) * 68;
    float mg = -1e30f;
    for (int c = 0; c < NCH; ++c) mg = fmaxf(mg, attn_part[base + c * 68]);
    float lg = 0.f;
    float wloc[NCH];
    for (int c = 0; c < NCH; ++c) {
      const float w = expf(attn_part[base + c * 68] - mg);
      wloc[c] = w;
      lg += attn_part[base + c * 68 + 1] * w;
    }
    const float invl = 1.f / lg;
    for (int c = 0; c < NCH; ++c) cw[bb * 2 + hr][c] = wloc[c] * invl;
  }
  __syncthreads();
  {
    const int bb = t >> 7, ir = t & 127;
    const int i = ibeg + ir;
    const int hh = i >> 6, hr = hh - ks * 2, d = i & 63;
    float s = 0.f;
#pragma unroll
    for (int c = 0; c < NCH; ++c)
      s += attn_part[((bb * 16 + hh) * NCH + c) * 68 + 2 + d] * cw[bb * 2 + hr][c];
    o[bb][ir] = s;
  }
  __syncthreads();
  float a00=0,a01=0,a02=0,a03=0, a10=0,a11=0,a12=0,a13=0;
#pragma unroll
  for (int r = 0; r < 2; ++r) {
    const int ir = kp * 2 + r;
    const float x0 = o[0][ir], x1 = o[1][ir];
    a00 += wbuf[r].x*x0; a01 += wbuf[r].y*x0; a02 += wbuf[r].z*x0; a03 += wbuf[r].w*x0;
    a10 += wbuf[r].x*x1; a11 += wbuf[r].y*x1; a12 += wbuf[r].z*x1; a13 += wbuf[r].w*x1;
  }
  redg[kp][0][jo4+0]=a00; redg[kp][0][jo4+1]=a01; redg[kp][0][jo4+2]=a02; redg[kp][0][jo4+3]=a03;
  redg[kp][1][jo4+0]=a10; redg[kp][1][jo4+1]=a11; redg[kp][1][jo4+2]=a12; redg[kp][1][jo4+3]=a13;
  __syncthreads();
  {
    const int qq = t >> 5, rest = t & 31;
    const int b2 = rest >> 4, jo = rest & 15;
    float s = 0.f;
#pragma unroll
    for (int k2 = 0; k2 < 8; ++k2) s += redg[qq * 8 + k2][b2][jo];
    redq2[qq][b2][jo] = s;
  }
  __syncthreads();
  if (t < 32) {
    const int b2 = t >> 4, jo = t & 15;
    float s = 0.f;
#pragma unroll
    for (int q2 = 0; q2 < 8; ++q2) s += redq2[q2][b2][jo];
    oproj_part[(size_t)(ks * 2 + b2) * D + jbase + jo] = s;
  }
}

// ---------------------------------------------------------------------------
// Gate+Up GEMV. grid(8, 64): ks = 128-row K-range, j-tile 64. BOTH wg and wu
// tiles prefetched before the prologue (overlap HBM with combine+norm).
// ---------------------------------------------------------------------------
__global__ __launch_bounds__(256) void k_gateup(
    const float* __restrict__ hbase, const float* __restrict__ oproj_part,
    float* __restrict__ h2_out, const float* __restrict__ ln2,
    const float* __restrict__ wg, const float* __restrict__ wu,
    float* __restrict__ gu_part, float scale)
{
  __shared__ float hn[2][D];
  __shared__ float redg[16][4][64];
  const int t = threadIdx.x;
  const int ks = blockIdx.x;   // 0..7
  const int cg = blockIdx.y;   // 0..63
  const int jbase = cg * 64;
  const int jo4 = (t & 15) * 4;
  const int kp = t >> 4;
  const int ib = ks * 128 + kp * 8;
  float4 wb[16];
#pragma unroll
  for (int r = 0; r < 8; ++r)
    wb[r] = *(const float4*)(wg + (size_t)(ib + r) * DFF + jbase + jo4);
#pragma unroll
  for (int r = 0; r < 8; ++r)
    wb[8 + r] = *(const float4*)(wu + (size_t)(ib + r) * DFF + jbase + jo4);
  prologue_norm(hbase, oproj_part, 8, scale, ln2, hn, h2_out);
  float g00=0,g01=0,g02=0,g03=0, g10=0,g11=0,g12=0,g13=0;
  float u00=0,u01=0,u02=0,u03=0, u10=0,u11=0,u12=0,u13=0;
#pragma unroll
  for (int r = 0; r < 8; ++r) {
    const float x0 = hn[0][ib + r], x1 = hn[1][ib + r];
    g00 += wb[r].x*x0; g01 += wb[r].y*x0; g02 += wb[r].z*x0; g03 += wb[r].w*x0;
    g10 += wb[r].x*x1; g11 += wb[r].y*x1; g12 += wb[r].z*x1; g13 += wb[r].w*x1;
    u00 += wb[8+r].x*x0; u01 += wb[8+r].y*x0; u02 += wb[8+r].z*x0; u03 += wb[8+r].w*x0;
    u10 += wb[8+r].x*x1; u11 += wb[8+r].y*x1; u12 += wb[8+r].z*x1; u13 += wb[8+r].w*x1;
  }
  redg[kp][0][jo4+0]=g00; redg[kp][0][jo4+1]=g01; redg[kp][0][jo4+2]=g02; redg[kp][0][jo4+3]=g03;
  redg[kp][1][jo4+0]=g10; redg[kp][1][jo4+1]=g11; redg[kp][1][jo4+2]=g12; redg[kp][1][jo4+3]=g13;
  redg[kp][2][jo4+0]=u00; redg[kp][2][jo4+1]=u01; redg[kp][2][jo4+2]=u02; redg[kp][2][jo4+3]=u03;
  redg[kp][3][jo4+0]=u10; redg[kp][3][jo4+1]=u11; redg[kp][3][jo4+2]=u12; redg[kp][3][jo4+3]=u13;
  __syncthreads();
  {
    const int sel = t >> 6;      // 0:g,b0 1:g,b1 2:u,b0 3:u,b1
    const int jo = t & 63;
    float s = 0.f;
#pragma unroll
    for (int k2 = 0; k2 < 16; ++k2) s += redg[k2][sel][jo];
    const int gm = sel >> 1, b = sel & 1;
    gu_part[(size_t)(ks * 4 + gm * 2 + b) * DFF + jbase + jo] = s;
  }
}

// ---------------------------------------------------------------------------
// Down GEMV. grid(8, 64): ks = 512-row K-range of DFF, j-tile 16.
// Full weight tile prefetched before act-combine. 8 K-partials out.
// ---------------------------------------------------------------------------
__global__ __launch_bounds__(256) void k_down(
    const float* __restrict__ gu_part, const float* __restrict__ wd,
    float* __restrict__ down_part)
{
  __shared__ float act[2][512];
  __shared__ float redg[64][2][16];
  __shared__ float redq2[8][2][16];
  const int t = threadIdx.x;
  const int ks = blockIdx.x;   // 0..7
  const int jt = blockIdx.y;   // 0..63
  const int ibeg = ks * 512;
  const int jbase = jt * 16;
  const int jo4 = (t & 3) * 4;
  const int kp = t >> 2;       // 0..63, 8 rows each
  float4 wbuf[8];
#pragma unroll
  for (int r = 0; r < 8; ++r)
    wbuf[r] = *(const float4*)(wd + (size_t)(ibeg + kp * 8 + r) * D + jbase + jo4);
#pragma unroll
  for (int u = 0; u < 4; ++u) {
    const int e = u * 256 + t;
    const int b = e >> 9, ir = e & 511;
    const int i = ibeg + ir;
    float g = 0.f, uu = 0.f;
#pragma unroll
    for (int k = 0; k < 8; ++k) {
      g  += gu_part[(size_t)(k * 4 + b) * DFF + i];
      uu += gu_part[(size_t)(k * 4 + 2 + b) * DFF + i];
    }
    act[b][ir] = silu_f(g) * uu;
  }
  __syncthreads();
  float a00=0,a01=0,a02=0,a03=0, a10=0,a11=0,a12=0,a13=0;
#pragma unroll
  for (int r = 0; r < 8; ++r) {
    const int lr = kp * 8 + r;
    const float x0 = act[0][lr], x1 = act[1][lr];
    a00 += wbuf[r].x*x0; a01 += wbuf[r].y*x0; a02 += wbuf[r].z*x0; a03 += wbuf[r].w*x0;
    a10 += wbuf[r].x*x1; a11 += wbuf[r].y*x1; a12 += wbuf[r].z*x1; a13 += wbuf[r].w*x1;
  }
  redg[kp][0][jo4+0]=a00; redg[kp][0][jo4+1]=a01; redg[kp][0][jo4+2]=a02; redg[kp][0][jo4+3]=a03;
  redg[kp][1][jo4+0]=a10; redg[kp][1][jo4+1]=a11; redg[kp][1][jo4+2]=a12; redg[kp][1][jo4+3]=a13;
  __syncthreads();
  {
    const int qq = t >> 5, rest = t & 31;
    const int b2 = rest >> 4, jo = rest & 15;
    float s = 0.f;
#pragma unroll
    for (int k2 = 0; k2 < 8; ++k2) s += redg[qq * 8 + k2][b2][jo];
    redq2[qq][b2][jo] = s;
  }
  __syncthreads();
  if (t < 32) {
    const int b2 = t >> 4, jo = t & 15;
    float s = 0.f;
#pragma unroll
    for (int q2 = 0; q2 < 8; ++q2) s += redq2[q2][b2][jo];
    down_part[(size_t)(ks * 2 + b2) * D + jbase + jo] = s;
  }
}

// ---------------------------------------------------------------------------
// Fused heads: blocks 0..127 stop-proj GEMV; blocks 128..143 FSQ head.
// Both start from lm_hidden = rmsnorm(h2 + scale*down, base_norm).
// ---------------------------------------------------------------------------
__global__ __launch_bounds__(256) void k_heads(
    const float* __restrict__ hbase, const float* __restrict__ down_part,
    const float* __restrict__ normw, const float* __restrict__ wsp,
    float* __restrict__ sproj_part,
    const float* __restrict__ fsq_in, const float* __restrict__ fsq_out,
    const float* __restrict__ embed,
    float* __restrict__ out_fsq, float* __restrict__ h_res, float scale)
{
  __shared__ float hn[2][D];
  const int t = threadIdx.x;
  const int bid = blockIdx.x;
  if (bid < 128) {
    __shared__ float redg[16][2][64];
    const int ks = bid >> 4, cg = bid & 15;
    const int jbase = cg * 64;
    const int jo4 = (t & 15) * 4;
    const int kp = t >> 4;
    const int ib = ks * 128 + kp * 8;
    float4 wbuf[8];
#pragma unroll
    for (int r = 0; r < 8; ++r)
      wbuf[r] = *(const float4*)(wsp + (size_t)(ib + r) * D + jbase + jo4);
    prologue_norm(hbase, down_part, 8, scale, normw, hn, nullptr);
    float a00=0,a01=0,a02=0,a03=0, a10=0,a11=0,a12=0,a13=0;
#pragma unroll
    for (int r = 0; r < 8; ++r) {
      const float x0 = hn[0][ib + r], x1 = hn[1][ib + r];
      a00 += wbuf[r].x*x0; a01 += wbuf[r].y*x0; a02 += wbuf[r].z*x0; a03 += wbuf[r].w*x0;
      a10 += wbuf[r].x*x1; a11 += wbuf[r].y*x1; a12 += wbuf[r].z*x1; a13 += wbuf[r].w*x1;
    }
    redg[kp][0][jo4+0]=a00; redg[kp][0][jo4+1]=a01; redg[kp][0][jo4+2]=a02; redg[kp][0][jo4+3]=a03;
    redg[kp][1][jo4+0]=a10; redg[kp][1][jo4+1]=a11; redg[kp][1][jo4+2]=a12; redg[kp][1][jo4+3]=a13;
    __syncthreads();
    if (t < 128) {
      const int b = t >> 6, jo = t & 63;
      float s = 0.f;
#pragma unroll
      for (int k2 = 0; k2 < 16; ++k2) s += redg[k2][b][jo];
      sproj_part[(size_t)(ks * 2 + b) * D + jbase + jo] = s;
    }
  } else {
    __shared__ float zred[4][2][32];
    __shared__ float zq[2][32];
    prologue_norm(hbase, down_part, 8, scale, normw, hn, nullptr);
    {
      const int c = t & 31, b = (t >> 5) & 1, kp = t >> 6;
      float s = 0.f;
      for (int i = kp * 256; i < kp * 256 + 256; ++i) s += hn[b][i] * fsq_in[i * 32 + c];
      zred[kp][b][c] = s;
    }
    __syncthreads();
    if (t < 64) {
      const int b = t >> 5, c = t & 31;
      float z = zred[0][b][c] + zred[1][b][c] + zred[2][b][c] + zred[3][b][c];
      z = tanhf(z);
      zq[b][c] = rintf(z * 3.5f) / 3.5f;
    }
    __syncthreads();
    if (t < 128) {
      const int b = t >> 6, jo = t & 63;
      const int j = (bid - 128) * 64 + jo;
      float s = 0.f;
#pragma unroll
      for (int c = 0; c < 32; ++c) s += zq[b][c] * fsq_out[c * D + j];
      out_fsq[b * D + j] = s;
      h_res[b * D + j] = s + embed[b * D + j];
    }
  }
}

// ---------------------------------------------------------------------------
__global__ __launch_bounds__(256) void k_stophead(
    const float* __restrict__ sproj_part, const float* __restrict__ bvec,
    const float* __restrict__ hw, const float* __restrict__ hb,
    float* __restrict__ out_stop)
{
  const int t = threadIdx.x;
  float acc0 = 0.f, acc1 = 0.f;
  for (int j = t; j < D; j += 256) {
    float v0 = bvec[j], v1 = bvec[j];
#pragma unroll
    for (int ks = 0; ks < 8; ++ks) {
      v0 += sproj_part[(ks * 2 + 0) * D + j];
      v1 += sproj_part[(ks * 2 + 1) * D + j];
    }
    acc0 += silu_f(v0) * hw[j];
    acc1 += silu_f(v1) * hw[j];
  }
  __shared__ float red[256];
  red[t] = acc0;
  __syncthreads();
  for (int s = 128; s > 0; s >>= 1) { if (t < s) red[t] += red[t + s]; __syncthreads(); }
  if (t == 0) out_stop[0] = red[0] + hb[0];
  __syncthreads();
  red[t] = acc1;
  __syncthreads();
  for (int s = 128; s > 0; s >>= 1) { if (t < s) red[t] += red[t + s]; __syncthreads(); }
  if (t == 0) out_stop[1] = red[0] + hb[0];
}

// ---------------------------------------------------------------------------
__global__ __launch_bounds__(256) void k_final(
    const float* __restrict__ hbase, const float* __restrict__ down_part,
    const float* __restrict__ normw, float* __restrict__ out_rh, float scale)
{
  __shared__ float hn[2][D];
  prologue_norm(hbase, down_part, 8, scale, normw, hn, nullptr);
  const int t = threadIdx.x;
  const int b = t >> 7;
  const int i0 = (t & 127) * 8;
#pragma unroll
  for (int u = 0; u < 8; ++u) out_rh[b * D + i0 + u] = hn[b][i0 + u];
}

// ---------------------------------------------------------------------------
extern "C" void kernel_launch(void* const* d_in, const int* in_sizes, int n_in,
                              void* d_out, int out_size, void* d_ws, size_t ws_size,
                              hipStream_t stream) {
  const float* embed      = (const float*)d_in[0];
  const int*   position   = (const int*)d_in[1];
  const float* base_k     = (const float*)d_in[2];
  const float* base_v     = (const float*)d_in[3];
  const float* res_k      = (const float*)d_in[4];
  const float* res_v      = (const float*)d_in[5];
  const float* base_ln1   = (const float*)d_in[6];
  const float* base_ln2   = (const float*)d_in[7];
  const float* base_wq    = (const float*)d_in[8];
  const float* base_wk    = (const float*)d_in[9];
  const float* base_wv    = (const float*)d_in[10];
  const float* base_wo    = (const float*)d_in[11];
  const float* base_wg    = (const float*)d_in[12];
  const float* base_wu    = (const float*)d_in[13];
  const float* base_wd    = (const float*)d_in[14];
  const float* base_norm  = (const float*)d_in[15];
  const float* res_ln1    = (const float*)d_in[16];
  const float* res_ln2    = (const float*)d_in[17];
  const float* res_wq     = (const float*)d_in[18];
  const float* res_wk     = (const float*)d_in[19];
  const float* res_wv     = (const float*)d_in[20];
  const float* res_wo     = (const float*)d_in[21];
  const float* res_wg     = (const float*)d_in[22];
  const float* res_wu     = (const float*)d_in[23];
  const float* res_wd     = (const float*)d_in[24];
  const float* res_norm   = (const float*)d_in[25];
  const float* fsq_in     = (const float*)d_in[26];
  const float* fsq_out    = (const float*)d_in[27];
  const float* stop_proj_w = (const float*)d_in[28];
  const float* stop_proj_b = (const float*)d_in[29];
  const float* stop_head_w = (const float*)d_in[30];
  const float* stop_head_b = (const float*)d_in[31];

  float* out = (float*)d_out;
  float* ws = (float*)d_ws;
  float* W_h     = ws + WS_H;
  float* W_h2    = ws + WS_H2;
  float* W_qkv   = ws + WS_QKV;
  float* W_attn  = ws + WS_ATTN;
  float* W_oproj = ws + WS_OPROJ;
  float* W_gu    = ws + WS_GU;
  float* W_down  = ws + WS_DOWN;
  float* W_sproj = ws + WS_SPROJ;

  const size_t cacheL_in  = (size_t)2 * NHEADS * S_CACHE * DH;   // 1048576
  const size_t cacheL_out = (size_t)2 * NHEADS * SP1 * DH;       // 1050624
  float* out_fsq  = out;
  float* out_rh   = out + 2048;
  float* out_stop = out + 4096;
  float* out_bnk  = out + 4098;
  float* out_bnv  = out_bnk + (size_t)NB_L * cacheL_out;
  float* out_rnk  = out_bnv + (size_t)NB_L * cacheL_out;
  float* out_rnv  = out_rnk + (size_t)NR_L * cacheL_out;

  const float scaleB = 1.4f / sqrtf((float)NB_L);
  const float scaleR = 1.4f / sqrtf((float)NR_L);

  auto run_layer = [&](const float* hbase, float* hout,
                       const float* ln1, const float* ln2,
                       const float* wq, const float* wk, const float* wv,
                       const float* wo, const float* wg, const float* wu,
                       const float* wd,
                       const float* kin, const float* vin,
                       float* kout, float* vout,
                       float scale, int has_prev) {
    k_qkv<<<512, 256, 0, stream>>>(hbase, W_down, hout, ln1,
                                   wq, wk, wv, W_qkv, scale, has_prev);
    k_attn<<<dim3(NCH, 32), 256, 0, stream>>>(W_qkv, position, kin, vin, kout, vout, W_attn);
    k_oproj<<<dim3(8, 64), 256, 0, stream>>>(W_attn, wo, W_oproj);
    k_gateup<<<dim3(8, 64), 256, 0, stream>>>(W_h, W_oproj, W_h2, ln2, wg, wu, W_gu, scale);
    k_down<<<dim3(8, 64), 256, 0, stream>>>(W_gu, wd, W_down);
  };

  for (int l = 0; l < NB_L; ++l) {
    run_layer(l == 0 ? embed : W_h2, W_h,
              base_ln1 + (size_t)l * D, base_ln2 + (size_t)l * D,
              base_wq + (size_t)l * D * D, base_wk + (size_t)l * D * D,
              base_wv + (size_t)l * D * D, base_wo + (size_t)l * D * D,
              base_wg + (size_t)l * D * DFF, base_wu + (size_t)l * D * DFF,
              base_wd + (size_t)l * DFF * D,
              base_k + (size_t)l * cacheL_in, base_v + (size_t)l * cacheL_in,
              out_bnk + (size_t)l * cacheL_out, out_bnv + (size_t)l * cacheL_out,
              scaleB, l > 0);
  }

  k_heads<<<144, 256, 0, stream>>>(W_h2, W_down, base_norm, stop_proj_w, W_sproj,
                                   fsq_in, fsq_out, embed, out_fsq, W_h, scaleB);
  k_stophead<<<1, 256, 0, stream>>>(W_sproj, stop_proj_b, stop_head_w, stop_head_b, out_stop);

  for (int l = 0; l < NR_L; ++l) {
    run_layer(l == 0 ? W_h : W_h2, l == 0 ? nullptr : W_h,
              res_ln1 + (size_t)l * D, res_ln2 + (size_t)l * D,
              res_wq + (size_t)l * D * D, res_wk + (size_t)l * D * D,
              res_wv + (size_t)l * D * D, res_wo + (size_t)l * D * D,
              res_wg + (size_t)l * D * DFF, res_wu + (size_t)l * D * DFF,
              res_wd + (size_t)l * DFF * D,
              res_k + (size_t)l * cacheL_in, res_v + (size_t)l * cacheL_in,
              out_rnk + (size_t)l * cacheL_out, out_rnv + (size_t)l * cacheL_out,
              scaleR, l > 0);
  }

  k_final<<<1, 256, 0, stream>>>(W_h2, W_down, res_norm, out_rh, scaleR);
}